// Round 4
// baseline (569.926 us; speedup 1.0000x reference)
//
#include <hip/hip_runtime.h>
#include <math.h>

// Scattering net: four-step register FFT (128 = 16 reg-DFT x 8 cross-group DFT).
// Thread (g=tid>>7, q=tid&127) owns 16 elements x[q][g+8m] of each line.
// Spectral storage permutation per axis: k = k1 + 16*k2 -> position p = 8*k1 + k2.
// psi pre-permuted into this layout (both axes) with 1/16384 folded in.
//
// Round-15: THREAD-MAJOR GLOBAL LAYOUTS. r14 (LDS pairing) confirmed DS was
// co-dominant; now VALU (~56%) leads, with ~50 VMEM-issue+addressing ops per
// thread in the prologues. Ubuf/psi/Xf are internal buffers -> re-layout
// thread-major: slot j of thread tid holds (row 16g+j, col q); each thread's
// 16 slots contiguous (64B bf16 / 128B f32) -> 4x dwordx4 (Ubuf), 8x dwordx4
// (psi/Xf) replace 16 scalar/x2 loads. k_psi folds the permutation at write.
// FFT core, LDS pairing, barriers, 66KB -> 2 blocks/CU all unchanged
// (r10 lesson: residency binds; r12 lesson: packed fp32 is issue-only).

#define SDIM 128
#define PLANE 16384
#define PITCH 129            // in storage elements
#define NT 1024
#define TWO_PI 6.28318530717958647692f

constexpr float W16R[8] = {1.f, 0.9238795325f, 0.7071067812f, 0.3826834324f,
                           0.f, -0.3826834324f, -0.7071067812f, -0.9238795325f};
constexpr float W16I[8] = {0.f, -0.3826834324f, -0.7071067812f, -0.9238795325f,
                           -1.f, -0.9238795325f, -0.7071067812f, -0.3826834324f};

__device__ __forceinline__ float fast_sqrtf(float x) {
  return __builtin_amdgcn_sqrtf(x);
}

// ---- packed bf16 complex <-> fp32 pair ----
__device__ __forceinline__ unsigned packbf(float re, float im) {
  const unsigned r = __float_as_uint(re) + 0x8000u;
  const unsigned i = __float_as_uint(im) + 0x8000u;
  return __builtin_amdgcn_perm(r, i, 0x07060302u);   // D = r.b3 r.b2 i.b3 i.b2
}
__device__ __forceinline__ void unpackbf(unsigned u, float& re, float& im) {
  re = __uint_as_float(u & 0xFFFF0000u);
  im = __uint_as_float(u << 16);
}

// storage-polymorphic LDS access
__device__ __forceinline__ void stC(float2* s, int idx, float re, float im) { s[idx] = make_float2(re, im); }
__device__ __forceinline__ void ldC(const float2* s, int idx, float& re, float& im) { const float2 v = s[idx]; re = v.x; im = v.y; }
__device__ __forceinline__ void stC(unsigned* s, int idx, float re, float im) { s[idx] = packbf(re, im); }
__device__ __forceinline__ void ldC(const unsigned* s, int idx, float& re, float& im) { unpackbf(s[idx], re, im); }

// wave-uniform twiddle table -> SGPRs. g = tid>>7 is wave-uniform (wave64).
__device__ __forceinline__ void load_tw(const float2* __restrict__ twg, int g,
                                        float* twr, float* twi) {
#pragma unroll
  for (int k = 1; k < 16; ++k) {
    const float2 w = twg[16 * g + k];
    twr[k] = __uint_as_float(__builtin_amdgcn_readfirstlane(__float_as_uint(w.x)));
    twi[k] = __uint_as_float(__builtin_amdgcn_readfirstlane(__float_as_uint(w.y)));
  }
}

template<bool INV>
__device__ __forceinline__ void bfly(float& ar, float& ai, float& br, float& bi, const int idx) {
  float tr, ti;
  if (idx == 0) {
    tr = br; ti = bi;
  } else if (idx == 4) {
    if (INV) { tr = -bi; ti = br; } else { tr = bi; ti = -br; }
  } else {
    const float wr = W16R[idx];
    const float wi = INV ? -W16I[idx] : W16I[idx];
    tr = br * wr - bi * wi;
    ti = br * wi + bi * wr;
  }
  br = ar - tr; bi = ai - ti;
  ar = ar + tr; ai = ai + ti;
}

#define CSWAP(re, im, a, b) { float _t = re[a]; re[a]=re[b]; re[b]=_t; _t = im[a]; im[a]=im[b]; im[b]=_t; }

template<bool INV>
__device__ __forceinline__ void dft16(float* re, float* im) {
  CSWAP(re, im, 1, 8) CSWAP(re, im, 2, 4) CSWAP(re, im, 3, 12)
  CSWAP(re, im, 5, 10) CSWAP(re, im, 7, 14) CSWAP(re, im, 11, 13)
#pragma unroll
  for (int ls = 1; ls <= 4; ++ls) {
    const int len = 1 << ls, half = len >> 1, tstep = 16 >> ls;
#pragma unroll
    for (int blk = 0; blk < 16; blk += len)
#pragma unroll
      for (int j = 0; j < half; ++j)
        bfly<INV>(re[blk + j], im[blk + j], re[blk + j + half], im[blk + j + half], j * tstep);
  }
}

template<bool INV>
__device__ __forceinline__ void dft8(float* re, float* im) {
  CSWAP(re, im, 1, 4) CSWAP(re, im, 3, 6)
#pragma unroll
  for (int ls = 1; ls <= 3; ++ls) {
    const int len = 1 << ls, half = len >> 1, tstep = 8 >> ls;
#pragma unroll
    for (int blk = 0; blk < 8; blk += len)
#pragma unroll
      for (int j = 0; j < half; ++j)
        bfly<INV>(re[blk + j], im[blk + j], re[blk + j + half], im[blk + j + half], j * tstep * 2);
  }
}

__device__ __forceinline__ void twmul_fwd(float* R, float* I, const float* twr, const float* twi) {
#pragma unroll
  for (int k = 1; k < 16; ++k) {
    const float r = R[k] * twr[k] - I[k] * twi[k];
    I[k] = R[k] * twi[k] + I[k] * twr[k]; R[k] = r;
  }
}
__device__ __forceinline__ void twmul_inv(float* R, float* I, const float* twr, const float* twi) {
#pragma unroll
  for (int k = 1; k < 16; ++k) {
    const float r = R[k] * twr[k] + I[k] * twi[k];
    I[k] = I[k] * twr[k] - R[k] * twi[k]; R[k] = r;
  }
}

// Forward fft2. In: x regs, R[m] = row q element (g+8m).
// Out: col-spectral regs: R[j] <-> plane pos (16g+j, q), j=0..15.
template<typename S>
__device__ __forceinline__ void fwd_fft2(float* R, float* I, S* sC,
                                         int g, int q, const float* twr, const float* twi) {
  const int rb = q * PITCH;
  dft16<false>(R, I);
  twmul_fwd(R, I, twr, twi);
  __syncthreads();                             // B0
#pragma unroll
  for (int k = 0; k < 16; ++k) stC(sC, rb + 8 * k + g, R[k], I[k]);   // D8 write2
  __syncthreads();                             // B1
#pragma unroll
  for (int t = 0; t < 8; ++t) {                                        // D1 read2
    ldC(sC, rb + 16 * g + t, R[t], I[t]);
    ldC(sC, rb + 16 * g + 8 + t, R[8 + t], I[8 + t]);
  }
  dft8<false>(R, I); dft8<false>(R + 8, I + 8);
#pragma unroll
  for (int k2 = 0; k2 < 8; ++k2) {             // same cells: no barrier; D1 write2
    stC(sC, rb + 16 * g + k2, R[k2], I[k2]);
    stC(sC, rb + 16 * g + 8 + k2, R[8 + k2], I[8 + k2]);
  }
  __syncthreads();                             // B2
#pragma unroll
  for (int m = 0; m < 16; ++m) ldC(sC, (g + 8 * m) * PITCH + q, R[m], I[m]);  // col b32
  dft16<false>(R, I);
  twmul_fwd(R, I, twr, twi);
#pragma unroll
  for (int k = 0; k < 16; ++k) stC(sC, (8 * k + g) * PITCH + q, R[k], I[k]);  // same cells, col b32
  __syncthreads();                             // B3
#pragma unroll
  for (int u = 0; u < 8; ++u) {                // per-pair base, offsets {0,+PITCH} -> read2
    const int bp = (16 * g + 2 * u) * PITCH + q;
    ldC(sC, bp, R[2 * u], I[2 * u]);
    ldC(sC, bp + PITCH, R[2 * u + 1], I[2 * u + 1]);
  }
  dft8<false>(R, I); dft8<false>(R + 8, I + 8);
}

// Inverse fft2 (unscaled; psi carries 1/16384). In: col-spectral regs (R[j] <-> row 16g+j).
// Out: x regs, R[m] = row q elem (g+8m). FIRST=true: skip B0.
template<bool FIRST, typename S>
__device__ __forceinline__ void inv_fft2(float* R, float* I, S* sC,
                                         int g, int q, const float* twr, const float* twi) {
  const int rb = q * PITCH;
  dft8<true>(R, I); dft8<true>(R + 8, I + 8);
  if constexpr (!FIRST) __syncthreads();       // B0
#pragma unroll
  for (int t = 0; t < 16; ++t) stC(sC, rb + 16 * g + t, R[t], I[t]);  // D1 write2
  __syncthreads();                             // B1
#pragma unroll
  for (int k = 0; k < 16; ++k) ldC(sC, rb + 8 * k + g, R[k], I[k]);   // D8 read2
  twmul_inv(R, I, twr, twi);
  dft16<true>(R, I);
#pragma unroll
  for (int m = 0; m < 16; ++m) stC(sC, rb + g + 8 * m, R[m], I[m]);   // same cells; D8 write2
  __syncthreads();                             // B2
#pragma unroll
  for (int u = 0; u < 8; ++u) {                // transpose read; pair base {0,+PITCH}
    const int bp = (16 * g + 2 * u) * PITCH + q;
    ldC(sC, bp, R[2 * u], I[2 * u]);
    ldC(sC, bp + PITCH, R[2 * u + 1], I[2 * u + 1]);
  }
  dft8<true>(R, I); dft8<true>(R + 8, I + 8);
#pragma unroll
  for (int u = 0; u < 8; ++u) {                // same cells: no barrier; pair base write2
    const int bp = (16 * g + 2 * u) * PITCH + q;
    stC(sC, bp, R[2 * u], I[2 * u]);
    stC(sC, bp + PITCH, R[2 * u + 1], I[2 * u + 1]);
  }
  __syncthreads();                             // B3
#pragma unroll
  for (int k = 0; k < 16; ++k) ldC(sC, (8 * k + g) * PITCH + q, R[k], I[k]);  // col b32
  twmul_inv(R, I, twr, twi);
  dft16<true>(R, I);
}

__device__ __forceinline__ float block_reduce_sum(float v, float* red, int tid) {
#pragma unroll
  for (int o = 32; o > 0; o >>= 1) v += __shfl_down(v, o);
  __syncthreads();
  if ((tid & 63) == 0) red[tid >> 6] = v;
  __syncthreads();
  float t = 0.0f;
  if (tid == 0) {
#pragma unroll
    for (int w = 0; w < 16; ++w) t += red[w];
  }
  return t;
}

// psi thread-major: psi[(plane*1024 + tid)*16 + j] = filter value at spectral
// position (row 16g+j, col q) (sigma-permuted axes), 1/16384 folded in.
// Block 0 also fills the w128^{g*k} twiddle table into twg.
__global__ __launch_bounds__(256) void k_psi(const float* __restrict__ mags,
                                             const float* __restrict__ phases,
                                             float2* __restrict__ psi,
                                             float2* __restrict__ twg) {
  if (blockIdx.x == 0 && threadIdx.x < 128) {
    const int gg = threadIdx.x >> 4, k = threadIdx.x & 15;
    float sn, cs;
    __sincosf(-TWO_PI * (float)(gg * k) * (1.0f / 128.0f), &sn, &cs);
    twg[threadIdx.x] = make_float2(cs, sn);
  }
  const int gid = blockIdx.x * 256 + threadIdx.x;      // < 24*16384
  const int p = gid >> 14;
  const int rem = gid & (PLANE - 1);
  const int tt = rem >> 4;                             // consumer tid
  const int j = rem & 15;                              // slot
  const int g = tt >> 7, q = tt & 127;
  const int pr = 16 * g + j, pc = q;                   // spectral position
  const int kr = (pr >> 3) + 16 * (pr & 7);            // sigma^-1
  const int kc = (pc >> 3) + 16 * (pc & 7);
  const int src = (p << 14) + kr * SDIM + kc;
  const float m = mags[src] * (1.0f / 16384.0f);
  float sn, cs;
  __sincosf(phases[src], &sn, &cs);
  psi[gid] = make_float2(m * cs, m * sn);
}

// fp32 LDS: Xf (thread-major) feeds everything downstream; ~5 us.
__global__ __launch_bounds__(NT) void k_img_fft(const float* __restrict__ img,
                                                float2* __restrict__ Xf,
                                                float* __restrict__ s0,
                                                const float2* __restrict__ twg) {
  __shared__ float2 sC[SDIM * PITCH];
  __shared__ float red[16];
  const int tid = threadIdx.x, b = blockIdx.x;
  const int g = __builtin_amdgcn_readfirstlane(tid >> 7);
  const int q = tid & 127;
  float twr[16], twi[16];
  load_tw(twg, g, twr, twi);
  const float* ip = img + b * PLANE;
  float sum = 0.0f;
#pragma unroll
  for (int kk = 0; kk < 16; ++kk) {
    const int e = tid + kk * NT;
    const float v = ip[e];
    sC[(e >> 7) * PITCH + (e & 127)] = make_float2(v, 0.0f);
    sum += v;
  }
  const float tot = block_reduce_sum(sum, red, tid);   // syncs publish sC
  if (tid == 0) s0[b] = tot * (1.0f / 16384.0f);
  __syncthreads();
  float R[16], I[16];
#pragma unroll
  for (int m = 0; m < 16; ++m) { R[m] = sC[q * PITCH + g + 8 * m].x; I[m] = 0.0f; }
  fwd_fft2(R, I, sC, g, q, twr, twi);
  float4* x4 = (float4*)(Xf + ((size_t)b * 1024 + tid) * 16);
#pragma unroll
  for (int i = 0; i < 8; ++i)
    x4[i] = make_float4(R[2 * i], I[2 * i], R[2 * i + 1], I[2 * i + 1]);
}

// Phase A: bid<1280: (j1=bid>>8, b=(bid&255)>>2, l1=bid&3):
//   u1=|ifft2(Xf.psi1)|, U=fft2(u1) -> Ubuf (thread-major packbf) + s1.
// bid>=1280: s1 j=5.
__global__ __launch_bounds__(NT) void k_scat_a(const float2* __restrict__ Xf,
                                               const float2* __restrict__ psi,
                                               float* __restrict__ s1num,
                                               unsigned* __restrict__ Ubuf,
                                               const float2* __restrict__ twg) {
  __shared__ unsigned sU[SDIM * PITCH];        // 66 KB -> 2 blocks/CU
  __shared__ float red[16];
  const int tid = threadIdx.x;
  const int g = __builtin_amdgcn_readfirstlane(tid >> 7);
  const int q = tid & 127;
  float twr[16], twi[16];
  load_tw(twg, g, twr, twi);
  const int bid = blockIdx.x;
  float R[16], I[16];

  if (bid < 1280) {
    const int j1 = bid >> 8;
    const int b = (bid & 255) >> 2;
    const int l1 = bid & 3;
    const float4* x4 = (const float4*)(Xf + ((size_t)b * 1024 + tid) * 16);
    const float4* p4 = (const float4*)(psi + ((size_t)(j1 * 4 + l1) * 1024 + tid) * 16);
#pragma unroll
    for (int i = 0; i < 8; ++i) {
      const float4 x = x4[i], v = p4[i];
      R[2 * i]     = x.x * v.x - x.y * v.y;  I[2 * i]     = x.x * v.y + x.y * v.x;
      R[2 * i + 1] = x.z * v.z - x.w * v.w;  I[2 * i + 1] = x.z * v.w + x.w * v.z;
    }
    inv_fft2<true>(R, I, sU, g, q, twr, twi);
    float s1sum = 0.0f;
#pragma unroll
    for (int m = 0; m < 16; ++m) {
      const float a = fast_sqrtf(R[m] * R[m] + I[m] * I[m]);
      s1sum += a; R[m] = a; I[m] = 0.0f;
    }
    fwd_fft2(R, I, sU, g, q, twr, twi);
    uint4 ob[4];
    unsigned* obs = (unsigned*)ob;
#pragma unroll
    for (int j = 0; j < 16; ++j) obs[j] = packbf(R[j], I[j]);
    uint4* o4 = (uint4*)(Ubuf + (size_t)((b * 5 + j1) * 4 + l1) * PLANE + tid * 16);
#pragma unroll
    for (int i = 0; i < 4; ++i) o4[i] = ob[i];
    const float tot = block_reduce_sum(s1sum, red, tid);
    if (tid == 0) atomicAdd(&s1num[b * 6 + j1], tot);
  } else {
    const int idx = bid - 1280;
    const int b = idx >> 2, l = idx & 3;
    const float4* x4 = (const float4*)(Xf + ((size_t)b * 1024 + tid) * 16);
    const float4* p4 = (const float4*)(psi + ((size_t)(20 + l) * 1024 + tid) * 16);
#pragma unroll
    for (int i = 0; i < 8; ++i) {
      const float4 x = x4[i], v = p4[i];
      R[2 * i]     = x.x * v.x - x.y * v.y;  I[2 * i]     = x.x * v.y + x.y * v.x;
      R[2 * i + 1] = x.z * v.z - x.w * v.w;  I[2 * i + 1] = x.z * v.w + x.w * v.z;
    }
    inv_fft2<true>(R, I, sU, g, q, twr, twi);
    float s = 0.0f;
#pragma unroll
    for (int m = 0; m < 16; ++m) s += fast_sqrtf(R[m] * R[m] + I[m] * I[m]);
    const float tot = block_reduce_sum(s, red, tid);
    if (tid == 0) atomicAdd(&s1num[b * 6 + 5], tot);
  }
}

// Phase B: one inner ifft per block. 15360 blocks (r9 structure; residency
// 2 blocks/CU is the binding resource -- do NOT hoist U into regs).
__global__ __launch_bounds__(NT) void k_scat_b(const float2* __restrict__ psi,
                                               const unsigned* __restrict__ Ubuf,
                                               float* __restrict__ s2num,
                                               const float2* __restrict__ twg) {
  __shared__ unsigned sU[SDIM * PITCH];        // 66 KB -> 2 blocks/CU
  __shared__ float red[16];
  const int tid = threadIdx.x;
  const int g = __builtin_amdgcn_readfirstlane(tid >> 7);
  const int q = tid & 127;
  float twr[16], twi[16];
  load_tw(twg, g, twr, twi);
  int t = blockIdx.x;
  const int l2 = t & 3; t >>= 2;
  const int pair = t % 15; t /= 15;
  const int l1 = t & 3;
  const int b = t >> 2;
  int j1 = 0, base = 0;
  if (pair >= 14)      { j1 = 4; base = 14; }
  else if (pair >= 12) { j1 = 3; base = 12; }
  else if (pair >= 9)  { j1 = 2; base = 9; }
  else if (pair >= 5)  { j1 = 1; base = 5; }
  const int j2 = j1 + 1 + (pair - base);
  float R[16], I[16];
  {
    const uint4* u4 = (const uint4*)(Ubuf + (size_t)((b * 5 + j1) * 4 + l1) * PLANE + tid * 16);
    uint4 ub[4];
#pragma unroll
    for (int i = 0; i < 4; ++i) ub[i] = u4[i];
    const unsigned* ubs = (const unsigned*)ub;
    const float4* p4 = (const float4*)(psi + ((size_t)(j2 * 4 + l2) * 1024 + tid) * 16);
#pragma unroll
    for (int i = 0; i < 8; ++i) {
      const float4 v = p4[i];
      float ur, ui;
      unpackbf(ubs[2 * i], ur, ui);
      R[2 * i] = ur * v.x - ui * v.y;      I[2 * i] = ur * v.y + ui * v.x;
      unpackbf(ubs[2 * i + 1], ur, ui);
      R[2 * i + 1] = ur * v.z - ui * v.w;  I[2 * i + 1] = ur * v.w + ui * v.z;
    }
  }
  inv_fft2<true>(R, I, sU, g, q, twr, twi);
  float vsum = 0.0f;
#pragma unroll
  for (int m = 0; m < 16; ++m) vsum += fast_sqrtf(R[m] * R[m] + I[m] * I[m]);
  const float tot = block_reduce_sum(vsum, red, tid);
  if (tid == 0) atomicAdd(&s2num[b * 15 + pair], tot);
}

// Fallback (ws too small): monolithic, U held in regs (will spill; correctness only).
__global__ __launch_bounds__(NT) void k_scat_mono(const float2* __restrict__ Xf,
                                                  const float2* __restrict__ psi,
                                                  float* __restrict__ s1num,
                                                  float* __restrict__ s2num,
                                                  const float2* __restrict__ twg) {
  __shared__ unsigned sU[SDIM * PITCH];
  __shared__ float red[16];
  const int tid = threadIdx.x;
  const int g = __builtin_amdgcn_readfirstlane(tid >> 7);
  const int q = tid & 127;
  float twr[16], twi[16];
  load_tw(twg, g, twr, twi);
  const int bid = blockIdx.x;
  float R[16], I[16];
  if (bid < 1280) {
    const int j1 = bid >> 8;
    const int b = (bid & 255) >> 2;
    const int l1 = bid & 3;
    const float4* x4 = (const float4*)(Xf + ((size_t)b * 1024 + tid) * 16);
    const float4* p4 = (const float4*)(psi + ((size_t)(j1 * 4 + l1) * 1024 + tid) * 16);
#pragma unroll
    for (int i = 0; i < 8; ++i) {
      const float4 x = x4[i], v = p4[i];
      R[2 * i]     = x.x * v.x - x.y * v.y;  I[2 * i]     = x.x * v.y + x.y * v.x;
      R[2 * i + 1] = x.z * v.z - x.w * v.w;  I[2 * i + 1] = x.z * v.w + x.w * v.z;
    }
    inv_fft2<true>(R, I, sU, g, q, twr, twi);
    float s1sum = 0.0f;
#pragma unroll
    for (int m = 0; m < 16; ++m) {
      const float a = fast_sqrtf(R[m] * R[m] + I[m] * I[m]);
      s1sum += a; R[m] = a; I[m] = 0.0f;
    }
    fwd_fft2(R, I, sU, g, q, twr, twi);
    float Ur[16], Ui[16];
#pragma unroll
    for (int k = 0; k < 16; ++k) { Ur[k] = R[k]; Ui[k] = I[k]; }
    {
      const float tot = block_reduce_sum(s1sum, red, tid);
      if (tid == 0) atomicAdd(&s1num[b * 6 + j1], tot);
    }
    const int pb = (j1 * (11 - j1)) >> 1;
    int plane = (j1 + 1) * 4;
#pragma unroll 1
    for (int j2 = j1 + 1; j2 <= 5; ++j2) {
      float vsum = 0.0f;
#pragma unroll 1
      for (int l2 = 0; l2 < 4; ++l2) {
        const float4* q4 = (const float4*)(psi + ((size_t)plane * 1024 + tid) * 16);
#pragma unroll
        for (int i = 0; i < 8; ++i) {
          const float4 v = q4[i];
          R[2 * i]     = Ur[2 * i] * v.x - Ui[2 * i] * v.y;
          I[2 * i]     = Ur[2 * i] * v.y + Ui[2 * i] * v.x;
          R[2 * i + 1] = Ur[2 * i + 1] * v.z - Ui[2 * i + 1] * v.w;
          I[2 * i + 1] = Ur[2 * i + 1] * v.w + Ui[2 * i + 1] * v.z;
        }
        inv_fft2<false>(R, I, sU, g, q, twr, twi);
#pragma unroll
        for (int m = 0; m < 16; ++m) vsum += fast_sqrtf(R[m] * R[m] + I[m] * I[m]);
        ++plane;
      }
      const float tot = block_reduce_sum(vsum, red, tid);
      if (tid == 0) atomicAdd(&s2num[b * 15 + pb + (j2 - j1 - 1)], tot);
    }
  } else {
    const int idx = bid - 1280;
    const int b = idx >> 2, l = idx & 3;
    const float4* x4 = (const float4*)(Xf + ((size_t)b * 1024 + tid) * 16);
    const float4* p4 = (const float4*)(psi + ((size_t)(20 + l) * 1024 + tid) * 16);
#pragma unroll
    for (int i = 0; i < 8; ++i) {
      const float4 x = x4[i], v = p4[i];
      R[2 * i]     = x.x * v.x - x.y * v.y;  I[2 * i]     = x.x * v.y + x.y * v.x;
      R[2 * i + 1] = x.z * v.z - x.w * v.w;  I[2 * i + 1] = x.z * v.w + x.w * v.z;
    }
    inv_fft2<true>(R, I, sU, g, q, twr, twi);
    float s = 0.0f;
#pragma unroll
    for (int m = 0; m < 16; ++m) s += fast_sqrtf(R[m] * R[m] + I[m] * I[m]);
    const float tot = block_reduce_sum(s, red, tid);
    if (tid == 0) atomicAdd(&s1num[b * 6 + 5], tot);
  }
}

__global__ __launch_bounds__(64) void k_final(const float* __restrict__ s0,
                                              const float* __restrict__ s1num,
                                              const float* __restrict__ s2num,
                                              const float* __restrict__ w1,
                                              const float* __restrict__ b1,
                                              const float* __restrict__ w2,
                                              const float* __restrict__ b2,
                                              const float* __restrict__ w3,
                                              const float* __restrict__ b3,
                                              float* __restrict__ out) {
  const int b = threadIdx.x;
  if (b >= 64) return;
  float x[22];
  x[0] = s0[b];
#pragma unroll
  for (int j = 0; j < 6; ++j) x[1 + j] = s1num[b * 6 + j] * (1.0f / (4.0f * 16384.0f));
#pragma unroll
  for (int p = 0; p < 15; ++p) x[7 + p] = s2num[b * 15 + p] * (1.0f / (16.0f * 16384.0f));
  float h1[16];
#pragma unroll
  for (int o = 0; o < 16; ++o) {
    float t = b1[o];
    for (int i = 0; i < 22; ++i) t += x[i] * w1[i * 16 + o];
    h1[o] = fmaxf(t, 0.0f);
  }
  float h2[16];
#pragma unroll
  for (int o = 0; o < 16; ++o) {
    float t = b2[o];
    for (int i = 0; i < 16; ++i) t += h1[i] * w2[i * 16 + o];
    h2[o] = fmaxf(t, 0.0f);
  }
  float t = b3[0];
#pragma unroll
  for (int i = 0; i < 16; ++i) t += h2[i] * w3[i];
  out[b] = 1.0f / (1.0f + expf(-t));
}

extern "C" void kernel_launch(void* const* d_in, const int* in_sizes, int n_in,
                              void* d_out, int out_size, void* d_ws, size_t ws_size,
                              hipStream_t stream) {
  (void)in_sizes; (void)n_in; (void)out_size;
  const float* image  = (const float*)d_in[0];
  const float* mags   = (const float*)d_in[1];
  const float* phases = (const float*)d_in[2];
  const float* w1 = (const float*)d_in[3];
  const float* b1 = (const float*)d_in[4];
  const float* w2 = (const float*)d_in[5];
  const float* b2 = (const float*)d_in[6];
  const float* w3 = (const float*)d_in[7];
  const float* b3 = (const float*)d_in[8];
  float* out = (float*)d_out;

  char* ws = (char*)d_ws;
  float2* psi = (float2*)ws;                       // 3,145,728 B
  float2* Xf  = (float2*)(ws + 3145728);           // 8,388,608 B
  float*  s0  = (float*)(ws + 11534336);           // 64
  float*  s1n = s0 + 64;                           // 384
  float*  s2n = s1n + 384;                         // 960
  float2* twg = (float2*)(s2n + 960);              // 128 float2
  unsigned* Ubuf = (unsigned*)(ws + 11542528);     // 83,886,080 B
  const size_t need = 11542528ull + 83886080ull;   // ~95.4 MB

  hipMemsetAsync(s1n, 0, (384 + 960) * sizeof(float), stream);
  k_psi<<<dim3(1536), dim3(256), 0, stream>>>(mags, phases, psi, twg);
  k_img_fft<<<dim3(64), dim3(NT), 0, stream>>>(image, Xf, s0, twg);
  if (ws_size >= need) {
    k_scat_a<<<dim3(1536), dim3(NT), 0, stream>>>(Xf, psi, s1n, Ubuf, twg);
    k_scat_b<<<dim3(15360), dim3(NT), 0, stream>>>(psi, Ubuf, s2n, twg);
  } else {
    k_scat_mono<<<dim3(1536), dim3(NT), 0, stream>>>(Xf, psi, s1n, s2n, twg);
  }
  k_final<<<dim3(1), dim3(64), 0, stream>>>(s0, s1n, s2n, w1, b1, w2, b2, w3, b3, out);
}

// Round 5
// 502.180 us; speedup vs baseline: 1.1349x; 1.1349x over previous
//
#include <hip/hip_runtime.h>
#include <math.h>

// Scattering net: four-step register FFT (128 = 16 reg-DFT x 8 cross-group DFT).
// Thread (g=tid>>7, q=tid&127) owns 16 elements x[q][g+8m] of each line.
// Spectral storage permutation per axis: k = k1 + 16*k2 -> position p = 8*k1 + k2.
// psi pre-permuted into this layout (both axes) with 1/16384 folded in.
//
// Round-16: GRANULE (vectorized-SoA) GLOBAL LAYOUTS. r15's thread-major
// (64B/thread contiguous) made dwordx4 lane-stride 64B -> intra-wave
// coalescing broken (1 line-sector per lane per instr, 4x L1 transactions)
// -> 382->397 regression despite VALU -10%. Fix: granule layout
// [frame][i][tid]: granule i = slots {2i,2i+1} (float4 psi/Xf) or {4i..4i+3}
// (uint4 Ubuf); instr i: addr = base + i*16KB + tid*16 -> lane stride 16B,
// fully coalesced, wide loads kept. LDS pairing (r14), SGPR twiddles (r13),
// fast_sqrt (r14) unchanged. 66KB -> 2 blocks/CU unchanged.

#define SDIM 128
#define PLANE 16384
#define PITCH 129            // in storage elements
#define NT 1024
#define TWO_PI 6.28318530717958647692f

constexpr float W16R[8] = {1.f, 0.9238795325f, 0.7071067812f, 0.3826834324f,
                           0.f, -0.3826834324f, -0.7071067812f, -0.9238795325f};
constexpr float W16I[8] = {0.f, -0.3826834324f, -0.7071067812f, -0.9238795325f,
                           -1.f, -0.9238795325f, -0.7071067812f, -0.3826834324f};

__device__ __forceinline__ float fast_sqrtf(float x) {
  return __builtin_amdgcn_sqrtf(x);
}

// ---- packed bf16 complex <-> fp32 pair ----
__device__ __forceinline__ unsigned packbf(float re, float im) {
  const unsigned r = __float_as_uint(re) + 0x8000u;
  const unsigned i = __float_as_uint(im) + 0x8000u;
  return __builtin_amdgcn_perm(r, i, 0x07060302u);   // D = r.b3 r.b2 i.b3 i.b2
}
__device__ __forceinline__ void unpackbf(unsigned u, float& re, float& im) {
  re = __uint_as_float(u & 0xFFFF0000u);
  im = __uint_as_float(u << 16);
}

// storage-polymorphic LDS access
__device__ __forceinline__ void stC(float2* s, int idx, float re, float im) { s[idx] = make_float2(re, im); }
__device__ __forceinline__ void ldC(const float2* s, int idx, float& re, float& im) { const float2 v = s[idx]; re = v.x; im = v.y; }
__device__ __forceinline__ void stC(unsigned* s, int idx, float re, float im) { s[idx] = packbf(re, im); }
__device__ __forceinline__ void ldC(const unsigned* s, int idx, float& re, float& im) { unpackbf(s[idx], re, im); }

// wave-uniform twiddle table -> SGPRs. g = tid>>7 is wave-uniform (wave64).
__device__ __forceinline__ void load_tw(const float2* __restrict__ twg, int g,
                                        float* twr, float* twi) {
#pragma unroll
  for (int k = 1; k < 16; ++k) {
    const float2 w = twg[16 * g + k];
    twr[k] = __uint_as_float(__builtin_amdgcn_readfirstlane(__float_as_uint(w.x)));
    twi[k] = __uint_as_float(__builtin_amdgcn_readfirstlane(__float_as_uint(w.y)));
  }
}

template<bool INV>
__device__ __forceinline__ void bfly(float& ar, float& ai, float& br, float& bi, const int idx) {
  float tr, ti;
  if (idx == 0) {
    tr = br; ti = bi;
  } else if (idx == 4) {
    if (INV) { tr = -bi; ti = br; } else { tr = bi; ti = -br; }
  } else {
    const float wr = W16R[idx];
    const float wi = INV ? -W16I[idx] : W16I[idx];
    tr = br * wr - bi * wi;
    ti = br * wi + bi * wr;
  }
  br = ar - tr; bi = ai - ti;
  ar = ar + tr; ai = ai + ti;
}

#define CSWAP(re, im, a, b) { float _t = re[a]; re[a]=re[b]; re[b]=_t; _t = im[a]; im[a]=im[b]; im[b]=_t; }

template<bool INV>
__device__ __forceinline__ void dft16(float* re, float* im) {
  CSWAP(re, im, 1, 8) CSWAP(re, im, 2, 4) CSWAP(re, im, 3, 12)
  CSWAP(re, im, 5, 10) CSWAP(re, im, 7, 14) CSWAP(re, im, 11, 13)
#pragma unroll
  for (int ls = 1; ls <= 4; ++ls) {
    const int len = 1 << ls, half = len >> 1, tstep = 16 >> ls;
#pragma unroll
    for (int blk = 0; blk < 16; blk += len)
#pragma unroll
      for (int j = 0; j < half; ++j)
        bfly<INV>(re[blk + j], im[blk + j], re[blk + j + half], im[blk + j + half], j * tstep);
  }
}

template<bool INV>
__device__ __forceinline__ void dft8(float* re, float* im) {
  CSWAP(re, im, 1, 4) CSWAP(re, im, 3, 6)
#pragma unroll
  for (int ls = 1; ls <= 3; ++ls) {
    const int len = 1 << ls, half = len >> 1, tstep = 8 >> ls;
#pragma unroll
    for (int blk = 0; blk < 8; blk += len)
#pragma unroll
      for (int j = 0; j < half; ++j)
        bfly<INV>(re[blk + j], im[blk + j], re[blk + j + half], im[blk + j + half], j * tstep * 2);
  }
}

__device__ __forceinline__ void twmul_fwd(float* R, float* I, const float* twr, const float* twi) {
#pragma unroll
  for (int k = 1; k < 16; ++k) {
    const float r = R[k] * twr[k] - I[k] * twi[k];
    I[k] = R[k] * twi[k] + I[k] * twr[k]; R[k] = r;
  }
}
__device__ __forceinline__ void twmul_inv(float* R, float* I, const float* twr, const float* twi) {
#pragma unroll
  for (int k = 1; k < 16; ++k) {
    const float r = R[k] * twr[k] + I[k] * twi[k];
    I[k] = I[k] * twr[k] - R[k] * twi[k]; R[k] = r;
  }
}

// Forward fft2. In: x regs, R[m] = row q element (g+8m).
// Out: col-spectral regs: R[j] <-> plane pos (16g+j, q), j=0..15.
template<typename S>
__device__ __forceinline__ void fwd_fft2(float* R, float* I, S* sC,
                                         int g, int q, const float* twr, const float* twi) {
  const int rb = q * PITCH;
  dft16<false>(R, I);
  twmul_fwd(R, I, twr, twi);
  __syncthreads();                             // B0
#pragma unroll
  for (int k = 0; k < 16; ++k) stC(sC, rb + 8 * k + g, R[k], I[k]);   // D8 write2
  __syncthreads();                             // B1
#pragma unroll
  for (int t = 0; t < 8; ++t) {                                        // D1 read2
    ldC(sC, rb + 16 * g + t, R[t], I[t]);
    ldC(sC, rb + 16 * g + 8 + t, R[8 + t], I[8 + t]);
  }
  dft8<false>(R, I); dft8<false>(R + 8, I + 8);
#pragma unroll
  for (int k2 = 0; k2 < 8; ++k2) {             // same cells: no barrier; D1 write2
    stC(sC, rb + 16 * g + k2, R[k2], I[k2]);
    stC(sC, rb + 16 * g + 8 + k2, R[8 + k2], I[8 + k2]);
  }
  __syncthreads();                             // B2
#pragma unroll
  for (int m = 0; m < 16; ++m) ldC(sC, (g + 8 * m) * PITCH + q, R[m], I[m]);  // col b32
  dft16<false>(R, I);
  twmul_fwd(R, I, twr, twi);
#pragma unroll
  for (int k = 0; k < 16; ++k) stC(sC, (8 * k + g) * PITCH + q, R[k], I[k]);  // same cells, col b32
  __syncthreads();                             // B3
#pragma unroll
  for (int u = 0; u < 8; ++u) {                // per-pair base, offsets {0,+PITCH} -> read2
    const int bp = (16 * g + 2 * u) * PITCH + q;
    ldC(sC, bp, R[2 * u], I[2 * u]);
    ldC(sC, bp + PITCH, R[2 * u + 1], I[2 * u + 1]);
  }
  dft8<false>(R, I); dft8<false>(R + 8, I + 8);
}

// Inverse fft2 (unscaled; psi carries 1/16384). In: col-spectral regs (R[j] <-> row 16g+j).
// Out: x regs, R[m] = row q elem (g+8m). FIRST=true: skip B0.
template<bool FIRST, typename S>
__device__ __forceinline__ void inv_fft2(float* R, float* I, S* sC,
                                         int g, int q, const float* twr, const float* twi) {
  const int rb = q * PITCH;
  dft8<true>(R, I); dft8<true>(R + 8, I + 8);
  if constexpr (!FIRST) __syncthreads();       // B0
#pragma unroll
  for (int t = 0; t < 16; ++t) stC(sC, rb + 16 * g + t, R[t], I[t]);  // D1 write2
  __syncthreads();                             // B1
#pragma unroll
  for (int k = 0; k < 16; ++k) ldC(sC, rb + 8 * k + g, R[k], I[k]);   // D8 read2
  twmul_inv(R, I, twr, twi);
  dft16<true>(R, I);
#pragma unroll
  for (int m = 0; m < 16; ++m) stC(sC, rb + g + 8 * m, R[m], I[m]);   // same cells; D8 write2
  __syncthreads();                             // B2
#pragma unroll
  for (int u = 0; u < 8; ++u) {                // transpose read; pair base {0,+PITCH}
    const int bp = (16 * g + 2 * u) * PITCH + q;
    ldC(sC, bp, R[2 * u], I[2 * u]);
    ldC(sC, bp + PITCH, R[2 * u + 1], I[2 * u + 1]);
  }
  dft8<true>(R, I); dft8<true>(R + 8, I + 8);
#pragma unroll
  for (int u = 0; u < 8; ++u) {                // same cells: no barrier; pair base write2
    const int bp = (16 * g + 2 * u) * PITCH + q;
    stC(sC, bp, R[2 * u], I[2 * u]);
    stC(sC, bp + PITCH, R[2 * u + 1], I[2 * u + 1]);
  }
  __syncthreads();                             // B3
#pragma unroll
  for (int k = 0; k < 16; ++k) ldC(sC, (8 * k + g) * PITCH + q, R[k], I[k]);  // col b32
  twmul_inv(R, I, twr, twi);
  dft16<true>(R, I);
}

__device__ __forceinline__ float block_reduce_sum(float v, float* red, int tid) {
#pragma unroll
  for (int o = 32; o > 0; o >>= 1) v += __shfl_down(v, o);
  __syncthreads();
  if ((tid & 63) == 0) red[tid >> 6] = v;
  __syncthreads();
  float t = 0.0f;
  if (tid == 0) {
#pragma unroll
    for (int w = 0; w < 16; ++w) t += red[w];
  }
  return t;
}

// psi granule layout: float4 granule (plane, i, tid) holds slots {2i, 2i+1}
// of consumer thread tid: value at spectral position (row 16g + 2i+e, col q),
// sigma-permuted axes, 1/16384 folded in. Flat float2 index:
// ((plane*8 + i)*1024 + tid)*2 + e. Block 0 also fills twg.
__global__ __launch_bounds__(256) void k_psi(const float* __restrict__ mags,
                                             const float* __restrict__ phases,
                                             float2* __restrict__ psi,
                                             float2* __restrict__ twg) {
  if (blockIdx.x == 0 && threadIdx.x < 128) {
    const int gg = threadIdx.x >> 4, k = threadIdx.x & 15;
    float sn, cs;
    __sincosf(-TWO_PI * (float)(gg * k) * (1.0f / 128.0f), &sn, &cs);
    twg[threadIdx.x] = make_float2(cs, sn);
  }
  const int gid = blockIdx.x * 256 + threadIdx.x;      // < 24*16384
  const int p = gid >> 14;
  const int rem = gid & (PLANE - 1);
  const int e = rem & 1;
  const int tt = (rem >> 1) & 1023;                    // consumer tid
  const int i = rem >> 11;                             // granule 0..7
  const int j = 2 * i + e;                             // slot
  const int g = tt >> 7, q = tt & 127;
  const int pr = 16 * g + j, pc = q;                   // spectral position
  const int kr = (pr >> 3) + 16 * (pr & 7);            // sigma^-1
  const int kc = (pc >> 3) + 16 * (pc & 7);
  const int src = (p << 14) + kr * SDIM + kc;
  const float m = mags[src] * (1.0f / 16384.0f);
  float sn, cs;
  __sincosf(phases[src], &sn, &cs);
  psi[gid] = make_float2(m * cs, m * sn);
}

// fp32 LDS: Xf (granule layout) feeds everything downstream; ~5 us.
__global__ __launch_bounds__(NT) void k_img_fft(const float* __restrict__ img,
                                                float2* __restrict__ Xf,
                                                float* __restrict__ s0,
                                                const float2* __restrict__ twg) {
  __shared__ float2 sC[SDIM * PITCH];
  __shared__ float red[16];
  const int tid = threadIdx.x, b = blockIdx.x;
  const int g = __builtin_amdgcn_readfirstlane(tid >> 7);
  const int q = tid & 127;
  float twr[16], twi[16];
  load_tw(twg, g, twr, twi);
  const float* ip = img + b * PLANE;
  float sum = 0.0f;
#pragma unroll
  for (int kk = 0; kk < 16; ++kk) {
    const int e = tid + kk * NT;
    const float v = ip[e];
    sC[(e >> 7) * PITCH + (e & 127)] = make_float2(v, 0.0f);
    sum += v;
  }
  const float tot = block_reduce_sum(sum, red, tid);   // syncs publish sC
  if (tid == 0) s0[b] = tot * (1.0f / 16384.0f);
  __syncthreads();
  float R[16], I[16];
#pragma unroll
  for (int m = 0; m < 16; ++m) { R[m] = sC[q * PITCH + g + 8 * m].x; I[m] = 0.0f; }
  fwd_fft2(R, I, sC, g, q, twr, twi);
  float4* x4 = (float4*)Xf + (size_t)b * 8192 + tid;
#pragma unroll
  for (int i = 0; i < 8; ++i)
    x4[i * 1024] = make_float4(R[2 * i], I[2 * i], R[2 * i + 1], I[2 * i + 1]);
}

// Phase A: bid<1280: (j1=bid>>8, b=(bid&255)>>2, l1=bid&3):
//   u1=|ifft2(Xf.psi1)|, U=fft2(u1) -> Ubuf (granule packbf) + s1.
// bid>=1280: s1 j=5.
__global__ __launch_bounds__(NT) void k_scat_a(const float2* __restrict__ Xf,
                                               const float2* __restrict__ psi,
                                               float* __restrict__ s1num,
                                               unsigned* __restrict__ Ubuf,
                                               const float2* __restrict__ twg) {
  __shared__ unsigned sU[SDIM * PITCH];        // 66 KB -> 2 blocks/CU
  __shared__ float red[16];
  const int tid = threadIdx.x;
  const int g = __builtin_amdgcn_readfirstlane(tid >> 7);
  const int q = tid & 127;
  float twr[16], twi[16];
  load_tw(twg, g, twr, twi);
  const int bid = blockIdx.x;
  float R[16], I[16];

  if (bid < 1280) {
    const int j1 = bid >> 8;
    const int b = (bid & 255) >> 2;
    const int l1 = bid & 3;
    const float4* x4 = (const float4*)Xf + (size_t)b * 8192 + tid;
    const float4* p4 = (const float4*)psi + (size_t)(j1 * 4 + l1) * 8192 + tid;
#pragma unroll
    for (int i = 0; i < 8; ++i) {
      const float4 x = x4[i * 1024], v = p4[i * 1024];
      R[2 * i]     = x.x * v.x - x.y * v.y;  I[2 * i]     = x.x * v.y + x.y * v.x;
      R[2 * i + 1] = x.z * v.z - x.w * v.w;  I[2 * i + 1] = x.z * v.w + x.w * v.z;
    }
    inv_fft2<true>(R, I, sU, g, q, twr, twi);
    float s1sum = 0.0f;
#pragma unroll
    for (int m = 0; m < 16; ++m) {
      const float a = fast_sqrtf(R[m] * R[m] + I[m] * I[m]);
      s1sum += a; R[m] = a; I[m] = 0.0f;
    }
    fwd_fft2(R, I, sU, g, q, twr, twi);
    uint4 ob[4];
    unsigned* obs = (unsigned*)ob;
#pragma unroll
    for (int j = 0; j < 16; ++j) obs[j] = packbf(R[j], I[j]);
    uint4* o4 = (uint4*)Ubuf + (size_t)((b * 5 + j1) * 4 + l1) * 4096 + tid;
#pragma unroll
    for (int i = 0; i < 4; ++i) o4[i * 1024] = ob[i];
    const float tot = block_reduce_sum(s1sum, red, tid);
    if (tid == 0) atomicAdd(&s1num[b * 6 + j1], tot);
  } else {
    const int idx = bid - 1280;
    const int b = idx >> 2, l = idx & 3;
    const float4* x4 = (const float4*)Xf + (size_t)b * 8192 + tid;
    const float4* p4 = (const float4*)psi + (size_t)(20 + l) * 8192 + tid;
#pragma unroll
    for (int i = 0; i < 8; ++i) {
      const float4 x = x4[i * 1024], v = p4[i * 1024];
      R[2 * i]     = x.x * v.x - x.y * v.y;  I[2 * i]     = x.x * v.y + x.y * v.x;
      R[2 * i + 1] = x.z * v.z - x.w * v.w;  I[2 * i + 1] = x.z * v.w + x.w * v.z;
    }
    inv_fft2<true>(R, I, sU, g, q, twr, twi);
    float s = 0.0f;
#pragma unroll
    for (int m = 0; m < 16; ++m) s += fast_sqrtf(R[m] * R[m] + I[m] * I[m]);
    const float tot = block_reduce_sum(s, red, tid);
    if (tid == 0) atomicAdd(&s1num[b * 6 + 5], tot);
  }
}

// Phase B: one inner ifft per block. 15360 blocks (r9 structure; residency
// 2 blocks/CU is the binding resource -- do NOT hoist U into regs).
__global__ __launch_bounds__(NT) void k_scat_b(const float2* __restrict__ psi,
                                               const unsigned* __restrict__ Ubuf,
                                               float* __restrict__ s2num,
                                               const float2* __restrict__ twg) {
  __shared__ unsigned sU[SDIM * PITCH];        // 66 KB -> 2 blocks/CU
  __shared__ float red[16];
  const int tid = threadIdx.x;
  const int g = __builtin_amdgcn_readfirstlane(tid >> 7);
  const int q = tid & 127;
  float twr[16], twi[16];
  load_tw(twg, g, twr, twi);
  int t = blockIdx.x;
  const int l2 = t & 3; t >>= 2;
  const int pair = t % 15; t /= 15;
  const int l1 = t & 3;
  const int b = t >> 2;
  int j1 = 0, base = 0;
  if (pair >= 14)      { j1 = 4; base = 14; }
  else if (pair >= 12) { j1 = 3; base = 12; }
  else if (pair >= 9)  { j1 = 2; base = 9; }
  else if (pair >= 5)  { j1 = 1; base = 5; }
  const int j2 = j1 + 1 + (pair - base);
  float R[16], I[16];
  {
    const uint4* u4 = (const uint4*)Ubuf + (size_t)((b * 5 + j1) * 4 + l1) * 4096 + tid;
    uint4 ub[4];
#pragma unroll
    for (int i = 0; i < 4; ++i) ub[i] = u4[i * 1024];
    const unsigned* ubs = (const unsigned*)ub;
    const float4* p4 = (const float4*)psi + (size_t)(j2 * 4 + l2) * 8192 + tid;
#pragma unroll
    for (int i = 0; i < 8; ++i) {
      const float4 v = p4[i * 1024];
      float ur, ui;
      unpackbf(ubs[2 * i], ur, ui);
      R[2 * i] = ur * v.x - ui * v.y;      I[2 * i] = ur * v.y + ui * v.x;
      unpackbf(ubs[2 * i + 1], ur, ui);
      R[2 * i + 1] = ur * v.z - ui * v.w;  I[2 * i + 1] = ur * v.w + ui * v.z;
    }
  }
  inv_fft2<true>(R, I, sU, g, q, twr, twi);
  float vsum = 0.0f;
#pragma unroll
  for (int m = 0; m < 16; ++m) vsum += fast_sqrtf(R[m] * R[m] + I[m] * I[m]);
  const float tot = block_reduce_sum(vsum, red, tid);
  if (tid == 0) atomicAdd(&s2num[b * 15 + pair], tot);
}

// Fallback (ws too small): monolithic, U held in regs (will spill; correctness only).
__global__ __launch_bounds__(NT) void k_scat_mono(const float2* __restrict__ Xf,
                                                  const float2* __restrict__ psi,
                                                  float* __restrict__ s1num,
                                                  float* __restrict__ s2num,
                                                  const float2* __restrict__ twg) {
  __shared__ unsigned sU[SDIM * PITCH];
  __shared__ float red[16];
  const int tid = threadIdx.x;
  const int g = __builtin_amdgcn_readfirstlane(tid >> 7);
  const int q = tid & 127;
  float twr[16], twi[16];
  load_tw(twg, g, twr, twi);
  const int bid = blockIdx.x;
  float R[16], I[16];
  if (bid < 1280) {
    const int j1 = bid >> 8;
    const int b = (bid & 255) >> 2;
    const int l1 = bid & 3;
    const float4* x4 = (const float4*)Xf + (size_t)b * 8192 + tid;
    const float4* p4 = (const float4*)psi + (size_t)(j1 * 4 + l1) * 8192 + tid;
#pragma unroll
    for (int i = 0; i < 8; ++i) {
      const float4 x = x4[i * 1024], v = p4[i * 1024];
      R[2 * i]     = x.x * v.x - x.y * v.y;  I[2 * i]     = x.x * v.y + x.y * v.x;
      R[2 * i + 1] = x.z * v.z - x.w * v.w;  I[2 * i + 1] = x.z * v.w + x.w * v.z;
    }
    inv_fft2<true>(R, I, sU, g, q, twr, twi);
    float s1sum = 0.0f;
#pragma unroll
    for (int m = 0; m < 16; ++m) {
      const float a = fast_sqrtf(R[m] * R[m] + I[m] * I[m]);
      s1sum += a; R[m] = a; I[m] = 0.0f;
    }
    fwd_fft2(R, I, sU, g, q, twr, twi);
    float Ur[16], Ui[16];
#pragma unroll
    for (int k = 0; k < 16; ++k) { Ur[k] = R[k]; Ui[k] = I[k]; }
    {
      const float tot = block_reduce_sum(s1sum, red, tid);
      if (tid == 0) atomicAdd(&s1num[b * 6 + j1], tot);
    }
    const int pb = (j1 * (11 - j1)) >> 1;
    int plane = (j1 + 1) * 4;
#pragma unroll 1
    for (int j2 = j1 + 1; j2 <= 5; ++j2) {
      float vsum = 0.0f;
#pragma unroll 1
      for (int l2 = 0; l2 < 4; ++l2) {
        const float4* q4 = (const float4*)psi + (size_t)plane * 8192 + tid;
#pragma unroll
        for (int i = 0; i < 8; ++i) {
          const float4 v = q4[i * 1024];
          R[2 * i]     = Ur[2 * i] * v.x - Ui[2 * i] * v.y;
          I[2 * i]     = Ur[2 * i] * v.y + Ui[2 * i] * v.x;
          R[2 * i + 1] = Ur[2 * i + 1] * v.z - Ui[2 * i + 1] * v.w;
          I[2 * i + 1] = Ur[2 * i + 1] * v.w + Ui[2 * i + 1] * v.z;
        }
        inv_fft2<false>(R, I, sU, g, q, twr, twi);
#pragma unroll
        for (int m = 0; m < 16; ++m) vsum += fast_sqrtf(R[m] * R[m] + I[m] * I[m]);
        ++plane;
      }
      const float tot = block_reduce_sum(vsum, red, tid);
      if (tid == 0) atomicAdd(&s2num[b * 15 + pb + (j2 - j1 - 1)], tot);
    }
  } else {
    const int idx = bid - 1280;
    const int b = idx >> 2, l = idx & 3;
    const float4* x4 = (const float4*)Xf + (size_t)b * 8192 + tid;
    const float4* p4 = (const float4*)psi + (size_t)(20 + l) * 8192 + tid;
#pragma unroll
    for (int i = 0; i < 8; ++i) {
      const float4 x = x4[i * 1024], v = p4[i * 1024];
      R[2 * i]     = x.x * v.x - x.y * v.y;  I[2 * i]     = x.x * v.y + x.y * v.x;
      R[2 * i + 1] = x.z * v.z - x.w * v.w;  I[2 * i + 1] = x.z * v.w + x.w * v.z;
    }
    inv_fft2<true>(R, I, sU, g, q, twr, twi);
    float s = 0.0f;
#pragma unroll
    for (int m = 0; m < 16; ++m) s += fast_sqrtf(R[m] * R[m] + I[m] * I[m]);
    const float tot = block_reduce_sum(s, red, tid);
    if (tid == 0) atomicAdd(&s1num[b * 6 + 5], tot);
  }
}

__global__ __launch_bounds__(64) void k_final(const float* __restrict__ s0,
                                              const float* __restrict__ s1num,
                                              const float* __restrict__ s2num,
                                              const float* __restrict__ w1,
                                              const float* __restrict__ b1,
                                              const float* __restrict__ w2,
                                              const float* __restrict__ b2,
                                              const float* __restrict__ w3,
                                              const float* __restrict__ b3,
                                              float* __restrict__ out) {
  const int b = threadIdx.x;
  if (b >= 64) return;
  float x[22];
  x[0] = s0[b];
#pragma unroll
  for (int j = 0; j < 6; ++j) x[1 + j] = s1num[b * 6 + j] * (1.0f / (4.0f * 16384.0f));
#pragma unroll
  for (int p = 0; p < 15; ++p) x[7 + p] = s2num[b * 15 + p] * (1.0f / (16.0f * 16384.0f));
  float h1[16];
#pragma unroll
  for (int o = 0; o < 16; ++o) {
    float t = b1[o];
    for (int i = 0; i < 22; ++i) t += x[i] * w1[i * 16 + o];
    h1[o] = fmaxf(t, 0.0f);
  }
  float h2[16];
#pragma unroll
  for (int o = 0; o < 16; ++o) {
    float t = b2[o];
    for (int i = 0; i < 16; ++i) t += h1[i] * w2[i * 16 + o];
    h2[o] = fmaxf(t, 0.0f);
  }
  float t = b3[0];
#pragma unroll
  for (int i = 0; i < 16; ++i) t += h2[i] * w3[i];
  out[b] = 1.0f / (1.0f + expf(-t));
}

extern "C" void kernel_launch(void* const* d_in, const int* in_sizes, int n_in,
                              void* d_out, int out_size, void* d_ws, size_t ws_size,
                              hipStream_t stream) {
  (void)in_sizes; (void)n_in; (void)out_size;
  const float* image  = (const float*)d_in[0];
  const float* mags   = (const float*)d_in[1];
  const float* phases = (const float*)d_in[2];
  const float* w1 = (const float*)d_in[3];
  const float* b1 = (const float*)d_in[4];
  const float* w2 = (const float*)d_in[5];
  const float* b2 = (const float*)d_in[6];
  const float* w3 = (const float*)d_in[7];
  const float* b3 = (const float*)d_in[8];
  float* out = (float*)d_out;

  char* ws = (char*)d_ws;
  float2* psi = (float2*)ws;                       // 3,145,728 B
  float2* Xf  = (float2*)(ws + 3145728);           // 8,388,608 B
  float*  s0  = (float*)(ws + 11534336);           // 64
  float*  s1n = s0 + 64;                           // 384
  float*  s2n = s1n + 384;                         // 960
  float2* twg = (float2*)(s2n + 960);              // 128 float2
  unsigned* Ubuf = (unsigned*)(ws + 11542528);     // 83,886,080 B
  const size_t need = 11542528ull + 83886080ull;   // ~95.4 MB

  hipMemsetAsync(s1n, 0, (384 + 960) * sizeof(float), stream);
  k_psi<<<dim3(1536), dim3(256), 0, stream>>>(mags, phases, psi, twg);
  k_img_fft<<<dim3(64), dim3(NT), 0, stream>>>(image, Xf, s0, twg);
  if (ws_size >= need) {
    k_scat_a<<<dim3(1536), dim3(NT), 0, stream>>>(Xf, psi, s1n, Ubuf, twg);
    k_scat_b<<<dim3(15360), dim3(NT), 0, stream>>>(psi, Ubuf, s2n, twg);
  } else {
    k_scat_mono<<<dim3(1536), dim3(NT), 0, stream>>>(Xf, psi, s1n, s2n, twg);
  }
  k_final<<<dim3(1), dim3(64), 0, stream>>>(s0, s1n, s2n, w1, b1, w2, b2, w3, b3, out);
}